// Round 11
// baseline (222.315 us; speedup 1.0000x reference)
//
#include <hip/hip_runtime.h>
#include <stdint.h>
#include <stddef.h>

#define Bsz 16384
#define Hsz 512
#define KG 1536   // K of gemm2 == row stride of A
#define KA 1024   // K of gemm1
#define NT3 48    // gemm2 K tiles of 32

typedef float f32x4 __attribute__((ext_vector_type(4)));
typedef short bf16x8 __attribute__((ext_vector_type(8)));
typedef unsigned short u16;
typedef unsigned int u32;

__device__ __forceinline__ u16 f2bf(float f) {
  union { float f; unsigned u; } v; v.f = f;
  return (u16)((v.u + 0x7fffu + ((v.u >> 16) & 1u)) >> 16);
}
__device__ __forceinline__ float bf2f(u16 h) {
  union { unsigned u; float f; } v; v.u = ((unsigned)h) << 16;
  return v.f;
}
__device__ __forceinline__ float sigm(float x) {
  return 1.0f / (1.0f + __expf(-x));
}
__device__ __forceinline__ float tanh_(float x) {
  x = fminf(fmaxf(x, -15.0f), 15.0f);
  float e = __expf(2.0f * x);
  return (e - 1.0f) / (e + 1.0f);
}

__device__ __forceinline__ void gload_lds16(const u16* g, u16* l) {
  __builtin_amdgcn_global_load_lds(
      (__attribute__((address_space(1))) void*)(g),
      (__attribute__((address_space(3))) void*)(l), 16, 0, 0);
}

// ---- cast h_prev | x_t into bf16 A[B][1536] (cols 0..1023) ----
__global__ __launch_bounds__(256) void prep_A_kernel(
    const float* __restrict__ h_prev, const float* __restrict__ x_t,
    u16* __restrict__ A) {
  const int b = blockIdx.x;
  const int q = threadIdx.x;
  const int qq = q & 127;
  const float4* src = (q < 128) ? (const float4*)h_prev : (const float4*)x_t;
  float4 v = src[(size_t)b * 128 + qq];
  ushort4 o;
  o.x = f2bf(v.x); o.y = f2bf(v.y); o.z = f2bf(v.z); o.w = f2bf(v.w);
  *(ushort4*)(A + (size_t)b * KG + (size_t)q * 4) = o;
}

// ---- transpose-cast: in[R][C] fp32 -> out[C][R] bf16 ----
__global__ __launch_bounds__(256) void transpose_cast_kernel(
    const float* __restrict__ in, u16* __restrict__ out, int R, int C) {
  __shared__ float tile[32][33];
  const int c0 = blockIdx.x * 32;
  const int r0 = blockIdx.y * 32;
  const int tx = threadIdx.x;
  const int ty = threadIdx.y;
  #pragma unroll
  for (int i = ty; i < 32; i += 8)
    tile[i][tx] = in[(size_t)(r0 + i) * C + (c0 + tx)];
  __syncthreads();
  #pragma unroll
  for (int i = ty; i < 32; i += 8)
    out[(size_t)(c0 + i) * R + (r0 + tx)] = f2bf(tile[tx][i]);
}

// ---- GEMM1: s = tanh(A[:,0:1024] @ Wst^T + delta*ws_last + bs) -> A[:,1024:1536]
__global__ __launch_bounds__(256, 2) void gemm1_kernel(
    const u16* __restrict__ A, const u16* __restrict__ Wst,
    const float* __restrict__ Ws, const float* __restrict__ bs,
    const float* __restrict__ delta, u16* __restrict__ Aout) {
  __shared__ __attribute__((aligned(16))) u16 Als[128][32];
  __shared__ __attribute__((aligned(16))) u16 Bls[128][32];
  const int t = threadIdx.x;
  const int w = t >> 6, l = t & 63;
  const int bm0 = blockIdx.y * 128;
  const int bn0 = blockIdx.x * 128;
  const int wm = w >> 1, wn = w & 1;

  f32x4 zv = {0.f, 0.f, 0.f, 0.f};
  f32x4 acc[4][4];
  #pragma unroll
  for (int i = 0; i < 4; ++i)
    #pragma unroll
    for (int j = 0; j < 4; ++j) acc[i][j] = zv;

  const int r = t >> 2, q = t & 3;
  const u16* gA0 = A + (size_t)(bm0 + r) * KG + q * 8;
  const u16* gA1 = A + (size_t)(bm0 + 64 + r) * KG + q * 8;
  const u16* gB0 = Wst + (size_t)(bn0 + r) * KA + q * 8;
  const u16* gB1 = Wst + (size_t)(bn0 + 64 + r) * KA + q * 8;
  u16* lA0 = &Als[0][0] + w * 512;
  u16* lA1 = &Als[0][0] + 2048 + w * 512;
  u16* lB0 = &Bls[0][0] + w * 512;
  u16* lB1 = &Bls[0][0] + 2048 + w * 512;

  const int frow = l & 15;
  const int kofs = (l >> 4) * 8;

  for (int kt = 0; kt < KA / 32; ++kt) {
    const int ko = kt * 32;
    gload_lds16(gA0 + ko, lA0);
    gload_lds16(gA1 + ko, lA1);
    gload_lds16(gB0 + ko, lB0);
    gload_lds16(gB1 + ko, lB1);
    __syncthreads();
    bf16x8 af[4], bfv[4];
    #pragma unroll
    for (int mi = 0; mi < 4; ++mi)
      af[mi] = *(const bf16x8*)&Als[wm * 64 + mi * 16 + frow][kofs];
    #pragma unroll
    for (int ni = 0; ni < 4; ++ni)
      bfv[ni] = *(const bf16x8*)&Bls[wn * 64 + ni * 16 + frow][kofs];
    #pragma unroll
    for (int mi = 0; mi < 4; ++mi)
      #pragma unroll
      for (int ni = 0; ni < 4; ++ni)
        acc[mi][ni] = __builtin_amdgcn_mfma_f32_16x16x32_bf16(
            af[mi], bfv[ni], acc[mi][ni], 0, 0, 0);
    __syncthreads();
  }

  #pragma unroll
  for (int ni = 0; ni < 4; ++ni) {
    const int col = bn0 + wn * 64 + ni * 16 + (l & 15);
    const float wsl = Ws[(size_t)1024 * 512 + col];
    const float bsv = bs[col];
    #pragma unroll
    for (int mi = 0; mi < 4; ++mi) {
      #pragma unroll
      for (int rr = 0; rr < 4; ++rr) {
        const int row = bm0 + wm * 64 + mi * 16 + (l >> 4) * 4 + rr;
        const float z = acc[mi][ni][rr] + delta[row] * wsl + bsv;
        Aout[(size_t)row * KG + 1024 + col] = f2bf(tanh_(z));
      }
    }
  }
}

// ---- GEMM2, lightweight-wave / multi-block occupancy (m97/m114 regime) ----
// Block = 256 threads (4 waves, 2M x 2N), tile 128 rows x 32 h (x5 gates).
// acc[4][5] f32x4 = 80 regs/thread -> ~3 blocks/CU (12 waves) resident;
// LDS 2 bufs x 18KB = 36 KB/block. Simple loop: STAGE(t+1) -> LDS reads ->
// 20 MFMA -> __syncthreads (compiler waitcnts; barrier drain absorbed by
// the other resident blocks, m114 overlap).
// Grid 2048 = 16 hb (low bits; 2 B-panels/XCD L2-pinned) x 128 rb.
// LDS chunk swizzle (r2-verified 0-conflict): store global chunk
// c^((row>>1)&3) at chunk c (pre-swizzled src, linear DMA dest); read
// chunk kq^((frow>>1)&3).
__global__ __launch_bounds__(256, 3) void gemm2_lw(
    const u16* __restrict__ A, const u16* __restrict__ Wgt,
    const float* __restrict__ bg, const float* __restrict__ c_prev,
    float* __restrict__ out) {
  __shared__ __attribute__((aligned(16))) u16 Als[2][128 * 32];  // 16 KB
  __shared__ __attribute__((aligned(16))) u16 Bls[2][160 * 32];  // 20 KB

  const int t5 = threadIdx.x;
  const int w = t5 >> 6;
  const int l = t5 & 63;

  const int bid = blockIdx.x;   // 2048 = 16 hb x 128 rb
  const int hb = bid & 15;
  const int rb = bid >> 4;
  const int bm0 = rb * 128;
  const int h0 = hb * 32;

  // ---- staging lists ----
  // A: 8 loads (s=0..7), wave w takes {w, w+4}. LDS rows 16s..16s+16.
  // B: 10 loads (s=0..9), wave w takes {w, w+4}, waves 2,3 add {w+6}.
  const u16* gA0; const u16* gA1;
  const u16* gB0; const u16* gB1; const u16* gB2 = Wgt;
  u32 loA0, loA1, loB0, loB1, loB2 = 0;
#define MKA(s, gp, lo) { int idx = (s) * 64 + l; int row = idx >> 2; \
    int ch = (idx & 3) ^ ((idx >> 3) & 3); \
    gp = A + (size_t)(bm0 + row) * KG + ch * 8; lo = (u32)(s) * 512; }
#define MKB(s, gp, lo) { int idx = (s) * 64 + l; int brow = idx >> 2; \
    int ch = (idx & 3) ^ ((idx >> 3) & 3); \
    int g = brow >> 5; int hl = brow & 31; \
    gp = Wgt + (size_t)(g * Hsz + h0 + hl) * KG + ch * 8; lo = (u32)(s) * 512; }
  MKA(w, gA0, loA0)
  MKA(w + 4, gA1, loA1)
  MKB(w, gB0, loB0)
  MKB(w + 4, gB1, loB1)
  if (w >= 2) { MKB(w + 6, gB2, loB2) }
#undef MKA
#undef MKB

#define STAGE(kt, bb) { \
    gload_lds16(gA0 + (size_t)(kt) * 32, &Als[bb][loA0]); \
    gload_lds16(gA1 + (size_t)(kt) * 32, &Als[bb][loA1]); \
    gload_lds16(gB0 + (size_t)(kt) * 32, &Bls[bb][loB0]); \
    gload_lds16(gB1 + (size_t)(kt) * 32, &Bls[bb][loB1]); \
    if (w >= 2) gload_lds16(gB2 + (size_t)(kt) * 32, &Bls[bb][loB2]); \
  }

  f32x4 zv = {0.f, 0.f, 0.f, 0.f};
  f32x4 acc[4][5];
  #pragma unroll
  for (int mi = 0; mi < 4; ++mi)
    #pragma unroll
    for (int g = 0; g < 5; ++g) acc[mi][g] = zv;

  const int wm = w >> 1;          // M half (64 rows)
  const int wn = w & 1;           // 16-col half of the 32-h window
  const int frow = l & 15;
  const int kq = l >> 4;
  const u32 axor = (u32)((kq ^ ((frow >> 1) & 3)) << 3);

  // prologue
  STAGE(0, 0)
  __syncthreads();

  for (int t = 0; t < NT3; ++t) {
    if (t + 1 < NT3) STAGE(t + 1, (t + 1) & 1)
    const u16* As = &Als[t & 1][0];
    const u16* Bs = &Bls[t & 1][0];
    bf16x8 af[4], bfv[5];
    #pragma unroll
    for (int mi = 0; mi < 4; ++mi)
      af[mi] = *(const bf16x8*)&As[(u32)(wm * 64 + mi * 16 + frow) * 32 + axor];
    #pragma unroll
    for (int g = 0; g < 5; ++g)
      bfv[g] = *(const bf16x8*)&Bs[(u32)(g * 32 + wn * 16 + frow) * 32 + axor];
    __builtin_amdgcn_s_setprio(1);
    #pragma unroll
    for (int g = 0; g < 5; ++g) {
      #pragma unroll
      for (int mi = 0; mi < 4; ++mi)
        acc[mi][g] = __builtin_amdgcn_mfma_f32_16x16x32_bf16(
            af[mi], bfv[g], acc[mi][g], 0, 0, 0);
    }
    __builtin_amdgcn_s_setprio(0);
    __syncthreads();   // drains vm (my t+1 DMA) + lgkm; all waves done with buf
  }
#undef STAGE

  const int hc = h0 + wn * 16 + frow;
  const float b_f = bg[hc];
  const float b_i = bg[Hsz + hc];
  const float b_T = bg[2 * Hsz + hc];
  const float b_z = bg[3 * Hsz + hc];
  const float b_o = bg[4 * Hsz + hc];
  #pragma unroll
  for (int mi = 0; mi < 4; ++mi) {
    #pragma unroll
    for (int rr = 0; rr < 4; ++rr) {
      const int row = bm0 + wm * 64 + mi * 16 + kq * 4 + rr;
      const float fg = sigm(acc[mi][0][rr] + b_f);
      const float ig = sigm(acc[mi][1][rr] + b_i);
      const float Tg = sigm(acc[mi][2][rr] + b_T);
      const float zg = tanh_(acc[mi][3][rr] + b_z);
      const float og = sigm(acc[mi][4][rr] + b_o);
      const float cp = c_prev[(size_t)row * Hsz + hc];
      const float st = bf2f(A[(size_t)row * KG + 1024 + hc]);
      const float c = fg * cp + ig * zg + Tg * st;
      const float h = og * tanh_(c);
      out[(size_t)row * Hsz + hc] = h;
      out[(size_t)Bsz * Hsz + (size_t)row * Hsz + hc] = c;
    }
  }
}

extern "C" void kernel_launch(void* const* d_in, const int* in_sizes, int n_in,
                              void* d_out, int out_size, void* d_ws, size_t ws_size,
                              hipStream_t stream) {
  const float* x_t    = (const float*)d_in[0];
  const float* delta  = (const float*)d_in[1];
  const float* h_prev = (const float*)d_in[2];
  const float* c_prev = (const float*)d_in[3];
  const float* Ws     = (const float*)d_in[4];
  const float* bs     = (const float*)d_in[5];
  const float* Wg     = (const float*)d_in[6];
  const float* bg     = (const float*)d_in[7];
  float* out = (float*)d_out;

  char* wsb = (char*)d_ws;
  u16* A   = (u16*)(wsb);                          // [16384][1536] bf16
  u16* Wst = (u16*)(wsb + (size_t)50331648);       // [512][1024]  bf16
  u16* Wgt = (u16*)(wsb + (size_t)51380224);       // [2560][1536] bf16

  prep_A_kernel<<<dim3(16384), dim3(256), 0, stream>>>(h_prev, x_t, A);
  transpose_cast_kernel<<<dim3(16, 32), dim3(32, 8), 0, stream>>>(Ws, Wst, 1024, 512);
  transpose_cast_kernel<<<dim3(80, 48), dim3(32, 8), 0, stream>>>(Wg, Wgt, 1536, 2560);
  gemm1_kernel<<<dim3(4, 128), dim3(256), 0, stream>>>(A, Wst, Ws, bs, delta, A);
  gemm2_lw<<<dim3(2048), dim3(256), 0, stream>>>(A, Wgt, bg, c_prev, out);
}